// Round 1
// baseline (572.417 us; speedup 1.0000x reference)
//
#include <hip/hip_runtime.h>

// GAT 2-layer, fp32, CSR-by-dst pipeline:
//   hist -> scan(3 kernels) -> scatter -> gemm1(+scores) -> agg1(softmax+sum+bias+relu)
//   -> gemm2(+scores) -> agg2 -> d_out
// No max-subtraction in softmax: scores are O(10), exp() safe in fp32, alpha shift-invariant.
// Every node has a self-loop, so deg>=1 and segment_max isfinite() branch is dead.

#define BS 256

__global__ __launch_bounds__(BS) void k_hist(const int* __restrict__ ei, int E, int E2,
                                             int* __restrict__ deg) {
    int i = blockIdx.x * BS + threadIdx.x;
    if (i >= E2) return;
    int d = (i < E) ? ei[E + i] : (i - E);   // row 1 = dst; tail = self loops
    atomicAdd(&deg[d], 1);
}

// 1024 elements per block: each thread owns 4, block-scan of thread sums.
__global__ __launch_bounds__(BS) void k_scan1(const int* __restrict__ deg, int n,
                                              int* __restrict__ row_ptr, int* __restrict__ bsum) {
    __shared__ int sh[BS];
    int t = threadIdx.x;
    int base = blockIdx.x * (BS * 4) + t * 4;
    int v0 = (base + 0 < n) ? deg[base + 0] : 0;
    int v1 = (base + 1 < n) ? deg[base + 1] : 0;
    int v2 = (base + 2 < n) ? deg[base + 2] : 0;
    int v3 = (base + 3 < n) ? deg[base + 3] : 0;
    int s = v0 + v1 + v2 + v3;
    sh[t] = s;
    __syncthreads();
    for (int off = 1; off < BS; off <<= 1) {
        int val = (t >= off) ? sh[t - off] : 0;
        __syncthreads();
        sh[t] += val;
        __syncthreads();
    }
    int excl = sh[t] - s;   // exclusive prefix of this thread's 4-chunk
    if (base + 0 < n) row_ptr[base + 0] = excl; excl += v0;
    if (base + 1 < n) row_ptr[base + 1] = excl; excl += v1;
    if (base + 2 < n) row_ptr[base + 2] = excl; excl += v2;
    if (base + 3 < n) row_ptr[base + 3] = excl;
    if (t == BS - 1) bsum[blockIdx.x] = sh[BS - 1];
}

__global__ __launch_bounds__(BS) void k_scan2(int* __restrict__ bsum, int nb) {
    __shared__ int sh[BS];
    int t = threadIdx.x;
    int v = (t < nb) ? bsum[t] : 0;
    sh[t] = v;
    __syncthreads();
    for (int off = 1; off < BS; off <<= 1) {
        int val = (t >= off) ? sh[t - off] : 0;
        __syncthreads();
        sh[t] += val;
        __syncthreads();
    }
    if (t < nb) bsum[t] = sh[t] - v;   // exclusive block offsets
}

__global__ __launch_bounds__(BS) void k_scan3(int* __restrict__ row_ptr, int* __restrict__ cursor,
                                              const int* __restrict__ bsum, int n) {
    int i = blockIdx.x * BS + threadIdx.x;
    if (i >= n) return;
    int v = row_ptr[i] + bsum[i >> 10];
    row_ptr[i] = v;
    cursor[i] = v;   // after scatter, cursor[i] == row_ptr[i+1]
}

__global__ __launch_bounds__(BS) void k_scatter(const int* __restrict__ ei, int E, int E2,
                                                int* __restrict__ cursor, int* __restrict__ col) {
    int i = blockIdx.x * BS + threadIdx.x;
    if (i >= E2) return;
    int s, d;
    if (i < E) { s = ei[i]; d = ei[E + i]; } else { s = d = i - E; }
    int pos = atomicAdd(&cursor[d], 1);
    col[pos] = s;
}

// xl1 = x @ W1 (128->64), plus per-node attention scores. W1 staged in LDS (32 KB),
// all lanes read same LDS address -> broadcast (no conflicts). Thread = node, 64 acc regs.
__global__ __launch_bounds__(BS) void k_gemm1(const float* __restrict__ x, const float* __restrict__ W,
                                              const float* __restrict__ asrc, const float* __restrict__ adst,
                                              float* __restrict__ xl, float* __restrict__ sc, int n) {
    __shared__ float4 w4[128 * 16];
    for (int i = threadIdx.x; i < 128 * 16; i += BS) w4[i] = ((const float4*)W)[i];
    __syncthreads();
    int node = blockIdx.x * BS + threadIdx.x;
    if (node >= n) return;
    float4 acc[16];
#pragma unroll
    for (int j = 0; j < 16; j++) acc[j] = make_float4(0.f, 0.f, 0.f, 0.f);
    const float4* xr = (const float4*)(x + (size_t)node * 128);
    for (int k4 = 0; k4 < 32; k4++) {
        float4 xv = xr[k4];
#pragma unroll
        for (int kk = 0; kk < 4; kk++) {
            float xk = (kk == 0) ? xv.x : (kk == 1) ? xv.y : (kk == 2) ? xv.z : xv.w;
            const float4* wr = &w4[(k4 * 4 + kk) * 16];
#pragma unroll
            for (int j = 0; j < 16; j++) {
                float4 w = wr[j];
                acc[j].x = fmaf(xk, w.x, acc[j].x);
                acc[j].y = fmaf(xk, w.y, acc[j].y);
                acc[j].z = fmaf(xk, w.z, acc[j].z);
                acc[j].w = fmaf(xk, w.w, acc[j].w);
            }
        }
    }
    float as0 = 0.f, as1 = 0.f, ad0 = 0.f, ad1 = 0.f;
#pragma unroll
    for (int j4 = 0; j4 < 16; j4++) {
        float4 v = acc[j4];
        float4 sa = ((const float4*)asrc)[j4];
        float4 da = ((const float4*)adst)[j4];
        float ts = v.x * sa.x + v.y * sa.y + v.z * sa.z + v.w * sa.w;
        float td = v.x * da.x + v.y * da.y + v.z * da.z + v.w * da.w;
        if (j4 < 8) { as0 += ts; ad0 += td; } else { as1 += ts; ad1 += td; }
    }
    float4* xo = (float4*)(xl + (size_t)node * 64);
#pragma unroll
    for (int j = 0; j < 16; j++) xo[j] = acc[j];
    ((float4*)sc)[node] = make_float4(as0, as1, ad0, ad1);
}

// One wave per node; lane = output channel (64 = HEADS*HID). Edge loop batched x4
// for memory-level parallelism. sc layout: [asn0, asn1, adn0, adn1] per node.
__global__ __launch_bounds__(BS) void k_agg1(const int* __restrict__ row_ptr, const int* __restrict__ cursor,
                                             const int* __restrict__ col, const float* __restrict__ xl,
                                             const float* __restrict__ sc, const float* __restrict__ b1,
                                             float* __restrict__ hout, int n) {
    int node = (blockIdx.x * BS + threadIdx.x) >> 6;
    int lane = threadIdx.x & 63;
    if (node >= n) return;
    int s0 = row_ptr[node], e1 = cursor[node];
    float2 adn = *(const float2*)&sc[(size_t)node * 4 + 2];
    float acc = 0.f, den0 = 0.f, den1 = 0.f;
    for (int i = s0; i < e1; i += 4) {
        int i1 = min(i + 1, e1 - 1), i2 = min(i + 2, e1 - 1), i3 = min(i + 3, e1 - 1);
        int sA = __builtin_amdgcn_readfirstlane(col[i]);
        int sB = __builtin_amdgcn_readfirstlane(col[i1]);
        int sC = __builtin_amdgcn_readfirstlane(col[i2]);
        int sD = __builtin_amdgcn_readfirstlane(col[i3]);
        float2 aA = *(const float2*)&sc[(size_t)sA * 4];
        float2 aB = *(const float2*)&sc[(size_t)sB * 4];
        float2 aC = *(const float2*)&sc[(size_t)sC * 4];
        float2 aD = *(const float2*)&sc[(size_t)sD * 4];
        float vA = xl[(size_t)sA * 64 + lane];
        float vB = xl[(size_t)sB * 64 + lane];
        float vC = xl[(size_t)sC * 64 + lane];
        float vD = xl[(size_t)sD * 64 + lane];
        {
            float e0 = aA.x + adn.x; e0 = e0 > 0.f ? e0 : 0.2f * e0;
            float e1v = aA.y + adn.y; e1v = e1v > 0.f ? e1v : 0.2f * e1v;
            float x0 = __expf(e0), x1 = __expf(e1v);
            den0 += x0; den1 += x1;
            acc = fmaf(lane < 32 ? x0 : x1, vA, acc);
        }
        if (i + 1 < e1) {
            float e0 = aB.x + adn.x; e0 = e0 > 0.f ? e0 : 0.2f * e0;
            float e1v = aB.y + adn.y; e1v = e1v > 0.f ? e1v : 0.2f * e1v;
            float x0 = __expf(e0), x1 = __expf(e1v);
            den0 += x0; den1 += x1;
            acc = fmaf(lane < 32 ? x0 : x1, vB, acc);
        }
        if (i + 2 < e1) {
            float e0 = aC.x + adn.x; e0 = e0 > 0.f ? e0 : 0.2f * e0;
            float e1v = aC.y + adn.y; e1v = e1v > 0.f ? e1v : 0.2f * e1v;
            float x0 = __expf(e0), x1 = __expf(e1v);
            den0 += x0; den1 += x1;
            acc = fmaf(lane < 32 ? x0 : x1, vC, acc);
        }
        if (i + 3 < e1) {
            float e0 = aD.x + adn.x; e0 = e0 > 0.f ? e0 : 0.2f * e0;
            float e1v = aD.y + adn.y; e1v = e1v > 0.f ? e1v : 0.2f * e1v;
            float x0 = __expf(e0), x1 = __expf(e1v);
            den0 += x0; den1 += x1;
            acc = fmaf(lane < 32 ? x0 : x1, vD, acc);
        }
    }
    float den = (lane < 32 ? den0 : den1) + 1e-16f;
    float o = acc / den + b1[lane];
    hout[(size_t)node * 64 + lane] = fmaxf(o, 0.f);   // ReLU after layer-1 GATConv
}

// xl2 = h @ W2 (64->32) + single-head scores.
__global__ __launch_bounds__(BS) void k_gemm2(const float* __restrict__ h, const float* __restrict__ W,
                                              const float* __restrict__ asrc, const float* __restrict__ adst,
                                              float* __restrict__ xl, float* __restrict__ sc, int n) {
    __shared__ float4 w4[64 * 8];
    for (int i = threadIdx.x; i < 64 * 8; i += BS) w4[i] = ((const float4*)W)[i];
    __syncthreads();
    int node = blockIdx.x * BS + threadIdx.x;
    if (node >= n) return;
    float4 acc[8];
#pragma unroll
    for (int j = 0; j < 8; j++) acc[j] = make_float4(0.f, 0.f, 0.f, 0.f);
    const float4* xr = (const float4*)(h + (size_t)node * 64);
    for (int k4 = 0; k4 < 16; k4++) {
        float4 xv = xr[k4];
#pragma unroll
        for (int kk = 0; kk < 4; kk++) {
            float xk = (kk == 0) ? xv.x : (kk == 1) ? xv.y : (kk == 2) ? xv.z : xv.w;
            const float4* wr = &w4[(k4 * 4 + kk) * 8];
#pragma unroll
            for (int j = 0; j < 8; j++) {
                float4 w = wr[j];
                acc[j].x = fmaf(xk, w.x, acc[j].x);
                acc[j].y = fmaf(xk, w.y, acc[j].y);
                acc[j].z = fmaf(xk, w.z, acc[j].z);
                acc[j].w = fmaf(xk, w.w, acc[j].w);
            }
        }
    }
    float as = 0.f, ad = 0.f;
#pragma unroll
    for (int j4 = 0; j4 < 8; j4++) {
        float4 v = acc[j4];
        float4 sa = ((const float4*)asrc)[j4];
        float4 da = ((const float4*)adst)[j4];
        as += v.x * sa.x + v.y * sa.y + v.z * sa.z + v.w * sa.w;
        ad += v.x * da.x + v.y * da.y + v.z * da.z + v.w * da.w;
    }
    float4* xo = (float4*)(xl + (size_t)node * 32);
#pragma unroll
    for (int j = 0; j < 8; j++) xo[j] = acc[j];
    ((float2*)sc)[node] = make_float2(as, ad);
}

// One wave per node, 32 output channels on lanes 0..31 (upper lanes duplicate compute, no store).
__global__ __launch_bounds__(BS) void k_agg2(const int* __restrict__ row_ptr, const int* __restrict__ cursor,
                                             const int* __restrict__ col, const float* __restrict__ xl,
                                             const float* __restrict__ sc, const float* __restrict__ b2,
                                             float* __restrict__ out, int n) {
    int node = (blockIdx.x * BS + threadIdx.x) >> 6;
    int lane = threadIdx.x & 63;
    int c = lane & 31;
    if (node >= n) return;
    int s0 = row_ptr[node], e1 = cursor[node];
    float adn = ((const float2*)sc)[node].y;
    float acc = 0.f, den = 0.f;
    for (int i = s0; i < e1; i += 4) {
        int i1 = min(i + 1, e1 - 1), i2 = min(i + 2, e1 - 1), i3 = min(i + 3, e1 - 1);
        int sA = __builtin_amdgcn_readfirstlane(col[i]);
        int sB = __builtin_amdgcn_readfirstlane(col[i1]);
        int sC = __builtin_amdgcn_readfirstlane(col[i2]);
        int sD = __builtin_amdgcn_readfirstlane(col[i3]);
        float aA = ((const float2*)sc)[sA].x;
        float aB = ((const float2*)sc)[sB].x;
        float aC = ((const float2*)sc)[sC].x;
        float aD = ((const float2*)sc)[sD].x;
        float vA = xl[(size_t)sA * 32 + c];
        float vB = xl[(size_t)sB * 32 + c];
        float vC = xl[(size_t)sC * 32 + c];
        float vD = xl[(size_t)sD * 32 + c];
        {
            float e = aA + adn; e = e > 0.f ? e : 0.2f * e;
            float x = __expf(e); den += x; acc = fmaf(x, vA, acc);
        }
        if (i + 1 < e1) { float e = aB + adn; e = e > 0.f ? e : 0.2f * e;
                          float x = __expf(e); den += x; acc = fmaf(x, vB, acc); }
        if (i + 2 < e1) { float e = aC + adn; e = e > 0.f ? e : 0.2f * e;
                          float x = __expf(e); den += x; acc = fmaf(x, vC, acc); }
        if (i + 3 < e1) { float e = aD + adn; e = e > 0.f ? e : 0.2f * e;
                          float x = __expf(e); den += x; acc = fmaf(x, vD, acc); }
    }
    if (lane < 32) out[(size_t)node * 32 + lane] = acc / (den + 1e-16f) + b2[lane];
}

extern "C" void kernel_launch(void* const* d_in, const int* in_sizes, int n_in,
                              void* d_out, int out_size, void* d_ws, size_t ws_size,
                              hipStream_t stream) {
    const float* x    = (const float*)d_in[0];
    const int*   ei   = (const int*)d_in[1];
    const float* W1   = (const float*)d_in[2];
    const float* as1  = (const float*)d_in[3];
    const float* ad1  = (const float*)d_in[4];
    const float* b1   = (const float*)d_in[5];
    const float* W2   = (const float*)d_in[6];
    const float* as2  = (const float*)d_in[7];
    const float* ad2  = (const float*)d_in[8];
    const float* b2   = (const float*)d_in[9];
    int n  = in_sizes[0] / 128;
    int E  = in_sizes[1] / 2;
    int E2 = E + n;

    char* w = (char*)d_ws;
    auto alloc = [&](size_t bytes) -> char* {
        char* p = w; w += (bytes + 255) / 256 * 256; return p;
    };
    int*   deg     = (int*)alloc((size_t)n * 4);
    int*   row_ptr = (int*)alloc((size_t)n * 4);
    int*   cursor  = (int*)alloc((size_t)n * 4);
    int*   bsum    = (int*)alloc(1024);
    int*   col     = (int*)alloc((size_t)E2 * 4);
    float* xl1     = (float*)alloc((size_t)n * 64 * 4);   // reused as xl2
    float* sc1     = (float*)alloc((size_t)n * 4 * 4);    // reused as sc2
    float* h       = (float*)alloc((size_t)n * 64 * 4);
    float* xl2 = xl1;
    float* sc2 = sc1;

    hipMemsetAsync(deg, 0, (size_t)n * 4, stream);
    int gE  = (E2 + BS - 1) / BS;
    int gN  = (n + BS - 1) / BS;
    int nb1 = (n + 1023) / 1024;
    int gW  = (n + 3) / 4;   // 4 waves (nodes) per 256-thread block

    k_hist   <<<gE, BS, 0, stream>>>(ei, E, E2, deg);
    k_scan1  <<<nb1, BS, 0, stream>>>(deg, n, row_ptr, bsum);
    k_scan2  <<<1, BS, 0, stream>>>(bsum, nb1);
    k_scan3  <<<gN, BS, 0, stream>>>(row_ptr, cursor, bsum, n);
    k_scatter<<<gE, BS, 0, stream>>>(ei, E, E2, cursor, col);
    k_gemm1  <<<gN, BS, 0, stream>>>(x, W1, as1, ad1, xl1, sc1, n);
    k_agg1   <<<gW, BS, 0, stream>>>(row_ptr, cursor, col, xl1, sc1, b1, h, n);
    k_gemm2  <<<gN, BS, 0, stream>>>(h, W2, as2, ad2, xl2, sc2, n);
    k_agg2   <<<gW, BS, 0, stream>>>(row_ptr, cursor, col, xl2, sc2, b2, (float*)d_out, n);
}

// Round 2
// 501.641 us; speedup vs baseline: 1.1411x; 1.1411x over previous
//
#include <hip/hip_runtime.h>

// GAT 2-layer, fp32. CSR-by-dst pipeline with XCD-phase-partitioned build:
//   hist(phase) -> scan(3) -> scatter(phase) -> gemm1(+scores) -> agg1 -> gemm2(+scores) -> agg2
// Self-loops are NOT materialized in the CSR; agg kernels add the self-loop term inline.
// No max-subtraction in softmax: scores are O(10), exp() safe in fp32, alpha shift-invariant.

#define BS 256

// Phase-partitioned histogram: block b handles dst range [phase*n/8,(phase+1)*n/8),
// phase = b&7 (round-robin block->XCD mapping keeps deg slice in one XCD's L2; this
// is a locality heuristic only — each edge counted exactly once regardless of mapping).
__global__ __launch_bounds__(BS) void k_hist(const int* __restrict__ ei, int E, int n,
                                             int* __restrict__ deg) {
    int b = blockIdx.x;
    int phase = b & 7, slice = b >> 3;
    int lo = (int)(((long long)phase * n) >> 3);
    int hi = (int)(((long long)(phase + 1) * n) >> 3);
    int base = (slice * BS + (int)threadIdx.x) * 4;
    if (base >= E) return;
    const int* dstp = ei + E;
    int d0, d1, d2, d3;
    if (base + 3 < E) {
        int4 v = *(const int4*)(dstp + base);
        d0 = v.x; d1 = v.y; d2 = v.z; d3 = v.w;
    } else {
        d0 = dstp[base];
        d1 = (base + 1 < E) ? dstp[base + 1] : -1;
        d2 = (base + 2 < E) ? dstp[base + 2] : -1;
        d3 = (base + 3 < E) ? dstp[base + 3] : -1;
    }
    if (d0 >= lo && d0 < hi) atomicAdd(&deg[d0], 1);
    if (d1 >= lo && d1 < hi) atomicAdd(&deg[d1], 1);
    if (d2 >= lo && d2 < hi) atomicAdd(&deg[d2], 1);
    if (d3 >= lo && d3 < hi) atomicAdd(&deg[d3], 1);
}

// 1024 elements per block: each thread owns 4, block-scan of thread sums.
__global__ __launch_bounds__(BS) void k_scan1(const int* __restrict__ deg, int n,
                                              int* __restrict__ row_ptr, int* __restrict__ bsum) {
    __shared__ int sh[BS];
    int t = threadIdx.x;
    int base = blockIdx.x * (BS * 4) + t * 4;
    int v0 = (base + 0 < n) ? deg[base + 0] : 0;
    int v1 = (base + 1 < n) ? deg[base + 1] : 0;
    int v2 = (base + 2 < n) ? deg[base + 2] : 0;
    int v3 = (base + 3 < n) ? deg[base + 3] : 0;
    int s = v0 + v1 + v2 + v3;
    sh[t] = s;
    __syncthreads();
    for (int off = 1; off < BS; off <<= 1) {
        int val = (t >= off) ? sh[t - off] : 0;
        __syncthreads();
        sh[t] += val;
        __syncthreads();
    }
    int excl = sh[t] - s;
    if (base + 0 < n) row_ptr[base + 0] = excl; excl += v0;
    if (base + 1 < n) row_ptr[base + 1] = excl; excl += v1;
    if (base + 2 < n) row_ptr[base + 2] = excl; excl += v2;
    if (base + 3 < n) row_ptr[base + 3] = excl;
    if (t == BS - 1) bsum[blockIdx.x] = sh[BS - 1];
}

__global__ __launch_bounds__(BS) void k_scan2(int* __restrict__ bsum, int nb) {
    __shared__ int sh[BS];
    int t = threadIdx.x;
    int v = (t < nb) ? bsum[t] : 0;
    sh[t] = v;
    __syncthreads();
    for (int off = 1; off < BS; off <<= 1) {
        int val = (t >= off) ? sh[t - off] : 0;
        __syncthreads();
        sh[t] += val;
        __syncthreads();
    }
    if (t < nb) bsum[t] = sh[t] - v;
}

__global__ __launch_bounds__(BS) void k_scan3(int* __restrict__ row_ptr, int* __restrict__ cursor,
                                              const int* __restrict__ bsum, int n) {
    int i = blockIdx.x * BS + threadIdx.x;
    if (i >= n) return;
    int v = row_ptr[i] + bsum[i >> 10];
    row_ptr[i] = v;
    cursor[i] = v;   // after scatter, cursor[i] == row_ptr[i+1]
}

// Phase-partitioned scatter: col writes land in a contiguous ~E/8 slice per phase,
// cursor atomics in a ~n/8 slice -> both stay in one XCD's L2 (heuristic), and the
// 4B-random-write -> 64B-HBM-writeback amplification disappears.
__global__ __launch_bounds__(BS) void k_scatter(const int* __restrict__ ei, int E, int n,
                                                int* __restrict__ cursor, int* __restrict__ col) {
    int b = blockIdx.x;
    int phase = b & 7, slice = b >> 3;
    int lo = (int)(((long long)phase * n) >> 3);
    int hi = (int)(((long long)(phase + 1) * n) >> 3);
    int base = (slice * BS + (int)threadIdx.x) * 4;
    if (base >= E) return;
    const int* dstp = ei + E;
    int d0, d1, d2, d3;
    if (base + 3 < E) {
        int4 v = *(const int4*)(dstp + base);
        d0 = v.x; d1 = v.y; d2 = v.z; d3 = v.w;
    } else {
        d0 = dstp[base];
        d1 = (base + 1 < E) ? dstp[base + 1] : -1;
        d2 = (base + 2 < E) ? dstp[base + 2] : -1;
        d3 = (base + 3 < E) ? dstp[base + 3] : -1;
    }
    bool m0 = (d0 >= lo && d0 < hi), m1 = (d1 >= lo && d1 < hi);
    bool m2 = (d2 >= lo && d2 < hi), m3 = (d3 >= lo && d3 < hi);
    if (!(m0 | m1 | m2 | m3)) return;
    int s0, s1, s2, s3;
    if (base + 3 < E) {
        int4 v = *(const int4*)(ei + base);
        s0 = v.x; s1 = v.y; s2 = v.z; s3 = v.w;
    } else {
        s0 = ei[base];
        s1 = (base + 1 < E) ? ei[base + 1] : 0;
        s2 = (base + 2 < E) ? ei[base + 2] : 0;
        s3 = (base + 3 < E) ? ei[base + 3] : 0;
    }
    if (m0) { int p = atomicAdd(&cursor[d0], 1); col[p] = s0; }
    if (m1) { int p = atomicAdd(&cursor[d1], 1); col[p] = s1; }
    if (m2) { int p = atomicAdd(&cursor[d2], 1); col[p] = s2; }
    if (m3) { int p = atomicAdd(&cursor[d3], 1); col[p] = s3; }
}

// xl1 = x @ W1 (128->64), plus per-node attention scores. W1 staged in LDS (32 KB).
__global__ __launch_bounds__(BS) void k_gemm1(const float* __restrict__ x, const float* __restrict__ W,
                                              const float* __restrict__ asrc, const float* __restrict__ adst,
                                              float* __restrict__ xl, float* __restrict__ sc, int n) {
    __shared__ float4 w4[128 * 16];
    for (int i = threadIdx.x; i < 128 * 16; i += BS) w4[i] = ((const float4*)W)[i];
    __syncthreads();
    int node = blockIdx.x * BS + threadIdx.x;
    if (node >= n) return;
    float4 acc[16];
#pragma unroll
    for (int j = 0; j < 16; j++) acc[j] = make_float4(0.f, 0.f, 0.f, 0.f);
    const float4* xr = (const float4*)(x + (size_t)node * 128);
    for (int k4 = 0; k4 < 32; k4++) {
        float4 xv = xr[k4];
#pragma unroll
        for (int kk = 0; kk < 4; kk++) {
            float xk = (kk == 0) ? xv.x : (kk == 1) ? xv.y : (kk == 2) ? xv.z : xv.w;
            const float4* wr = &w4[(k4 * 4 + kk) * 16];
#pragma unroll
            for (int j = 0; j < 16; j++) {
                float4 w = wr[j];
                acc[j].x = fmaf(xk, w.x, acc[j].x);
                acc[j].y = fmaf(xk, w.y, acc[j].y);
                acc[j].z = fmaf(xk, w.z, acc[j].z);
                acc[j].w = fmaf(xk, w.w, acc[j].w);
            }
        }
    }
    float as0 = 0.f, as1 = 0.f, ad0 = 0.f, ad1 = 0.f;
#pragma unroll
    for (int j4 = 0; j4 < 16; j4++) {
        float4 v = acc[j4];
        float4 sa = ((const float4*)asrc)[j4];
        float4 da = ((const float4*)adst)[j4];
        float ts = v.x * sa.x + v.y * sa.y + v.z * sa.z + v.w * sa.w;
        float td = v.x * da.x + v.y * da.y + v.z * da.z + v.w * da.w;
        if (j4 < 8) { as0 += ts; ad0 += td; } else { as1 += ts; ad1 += td; }
    }
    float4* xo = (float4*)(xl + (size_t)node * 64);
#pragma unroll
    for (int j = 0; j < 16; j++) xo[j] = acc[j];
    ((float4*)sc)[node] = make_float4(as0, as1, ad0, ad1);
}

// One wave per node; lane = output channel (64 = HEADS*HID). Edge loop batched x4.
// Self-loop handled inline (not in CSR). sc layout: [asn0, asn1, adn0, adn1].
__global__ __launch_bounds__(BS) void k_agg1(const int* __restrict__ row_ptr, const int* __restrict__ cursor,
                                             const int* __restrict__ col, const float* __restrict__ xl,
                                             const float* __restrict__ sc, const float* __restrict__ b1,
                                             float* __restrict__ hout, int n) {
    int node = (blockIdx.x * BS + threadIdx.x) >> 6;
    int lane = threadIdx.x & 63;
    if (node >= n) return;
    int s0 = row_ptr[node], e1 = cursor[node];
    float2 asn = *(const float2*)&sc[(size_t)node * 4];
    float2 adn = *(const float2*)&sc[(size_t)node * 4 + 2];
    // self-loop term
    float es0 = asn.x + adn.x; es0 = es0 > 0.f ? es0 : 0.2f * es0;
    float es1 = asn.y + adn.y; es1 = es1 > 0.f ? es1 : 0.2f * es1;
    float xs0 = __expf(es0), xs1 = __expf(es1);
    float den0 = xs0, den1 = xs1;
    float acc = (lane < 32 ? xs0 : xs1) * xl[(size_t)node * 64 + lane];
    for (int i = s0; i < e1; i += 4) {
        int i1 = min(i + 1, e1 - 1), i2 = min(i + 2, e1 - 1), i3 = min(i + 3, e1 - 1);
        int sA = __builtin_amdgcn_readfirstlane(col[i]);
        int sB = __builtin_amdgcn_readfirstlane(col[i1]);
        int sC = __builtin_amdgcn_readfirstlane(col[i2]);
        int sD = __builtin_amdgcn_readfirstlane(col[i3]);
        float2 aA = *(const float2*)&sc[(size_t)sA * 4];
        float2 aB = *(const float2*)&sc[(size_t)sB * 4];
        float2 aC = *(const float2*)&sc[(size_t)sC * 4];
        float2 aD = *(const float2*)&sc[(size_t)sD * 4];
        float vA = xl[(size_t)sA * 64 + lane];
        float vB = xl[(size_t)sB * 64 + lane];
        float vC = xl[(size_t)sC * 64 + lane];
        float vD = xl[(size_t)sD * 64 + lane];
        {
            float e0 = aA.x + adn.x; e0 = e0 > 0.f ? e0 : 0.2f * e0;
            float e1v = aA.y + adn.y; e1v = e1v > 0.f ? e1v : 0.2f * e1v;
            float x0 = __expf(e0), x1 = __expf(e1v);
            den0 += x0; den1 += x1;
            acc = fmaf(lane < 32 ? x0 : x1, vA, acc);
        }
        if (i + 1 < e1) {
            float e0 = aB.x + adn.x; e0 = e0 > 0.f ? e0 : 0.2f * e0;
            float e1v = aB.y + adn.y; e1v = e1v > 0.f ? e1v : 0.2f * e1v;
            float x0 = __expf(e0), x1 = __expf(e1v);
            den0 += x0; den1 += x1;
            acc = fmaf(lane < 32 ? x0 : x1, vB, acc);
        }
        if (i + 2 < e1) {
            float e0 = aC.x + adn.x; e0 = e0 > 0.f ? e0 : 0.2f * e0;
            float e1v = aC.y + adn.y; e1v = e1v > 0.f ? e1v : 0.2f * e1v;
            float x0 = __expf(e0), x1 = __expf(e1v);
            den0 += x0; den1 += x1;
            acc = fmaf(lane < 32 ? x0 : x1, vC, acc);
        }
        if (i + 3 < e1) {
            float e0 = aD.x + adn.x; e0 = e0 > 0.f ? e0 : 0.2f * e0;
            float e1v = aD.y + adn.y; e1v = e1v > 0.f ? e1v : 0.2f * e1v;
            float x0 = __expf(e0), x1 = __expf(e1v);
            den0 += x0; den1 += x1;
            acc = fmaf(lane < 32 ? x0 : x1, vD, acc);
        }
    }
    float den = (lane < 32 ? den0 : den1) + 1e-16f;
    float o = acc / den + b1[lane];
    hout[(size_t)node * 64 + lane] = fmaxf(o, 0.f);   // ReLU after layer-1 GATConv
}

// xl2 = h @ W2 (64->32) + single-head scores.
__global__ __launch_bounds__(BS) void k_gemm2(const float* __restrict__ h, const float* __restrict__ W,
                                              const float* __restrict__ asrc, const float* __restrict__ adst,
                                              float* __restrict__ xl, float* __restrict__ sc, int n) {
    __shared__ float4 w4[64 * 8];
    for (int i = threadIdx.x; i < 64 * 8; i += BS) w4[i] = ((const float4*)W)[i];
    __syncthreads();
    int node = blockIdx.x * BS + threadIdx.x;
    if (node >= n) return;
    float4 acc[8];
#pragma unroll
    for (int j = 0; j < 8; j++) acc[j] = make_float4(0.f, 0.f, 0.f, 0.f);
    const float4* xr = (const float4*)(h + (size_t)node * 64);
    for (int k4 = 0; k4 < 16; k4++) {
        float4 xv = xr[k4];
#pragma unroll
        for (int kk = 0; kk < 4; kk++) {
            float xk = (kk == 0) ? xv.x : (kk == 1) ? xv.y : (kk == 2) ? xv.z : xv.w;
            const float4* wr = &w4[(k4 * 4 + kk) * 8];
#pragma unroll
            for (int j = 0; j < 8; j++) {
                float4 w = wr[j];
                acc[j].x = fmaf(xk, w.x, acc[j].x);
                acc[j].y = fmaf(xk, w.y, acc[j].y);
                acc[j].z = fmaf(xk, w.z, acc[j].z);
                acc[j].w = fmaf(xk, w.w, acc[j].w);
            }
        }
    }
    float as = 0.f, ad = 0.f;
#pragma unroll
    for (int j4 = 0; j4 < 8; j4++) {
        float4 v = acc[j4];
        float4 sa = ((const float4*)asrc)[j4];
        float4 da = ((const float4*)adst)[j4];
        as += v.x * sa.x + v.y * sa.y + v.z * sa.z + v.w * sa.w;
        ad += v.x * da.x + v.y * da.y + v.z * da.z + v.w * da.w;
    }
    float4* xo = (float4*)(xl + (size_t)node * 32);
#pragma unroll
    for (int j = 0; j < 8; j++) xo[j] = acc[j];
    ((float2*)sc)[node] = make_float2(as, ad);
}

// One wave per node, 32 output channels (lanes 0..31 store; upper lanes duplicate).
__global__ __launch_bounds__(BS) void k_agg2(const int* __restrict__ row_ptr, const int* __restrict__ cursor,
                                             const int* __restrict__ col, const float* __restrict__ xl,
                                             const float* __restrict__ sc, const float* __restrict__ b2,
                                             float* __restrict__ out, int n) {
    int node = (blockIdx.x * BS + threadIdx.x) >> 6;
    int lane = threadIdx.x & 63;
    int c = lane & 31;
    if (node >= n) return;
    int s0 = row_ptr[node], e1 = cursor[node];
    float2 sn = ((const float2*)sc)[node];   // (asn, adn)
    float adn = sn.y;
    // self-loop term
    float es = sn.x + adn; es = es > 0.f ? es : 0.2f * es;
    float xs = __expf(es);
    float den = xs;
    float acc = xs * xl[(size_t)node * 32 + c];
    for (int i = s0; i < e1; i += 4) {
        int i1 = min(i + 1, e1 - 1), i2 = min(i + 2, e1 - 1), i3 = min(i + 3, e1 - 1);
        int sA = __builtin_amdgcn_readfirstlane(col[i]);
        int sB = __builtin_amdgcn_readfirstlane(col[i1]);
        int sC = __builtin_amdgcn_readfirstlane(col[i2]);
        int sD = __builtin_amdgcn_readfirstlane(col[i3]);
        float aA = ((const float2*)sc)[sA].x;
        float aB = ((const float2*)sc)[sB].x;
        float aC = ((const float2*)sc)[sC].x;
        float aD = ((const float2*)sc)[sD].x;
        float vA = xl[(size_t)sA * 32 + c];
        float vB = xl[(size_t)sB * 32 + c];
        float vC = xl[(size_t)sC * 32 + c];
        float vD = xl[(size_t)sD * 32 + c];
        {
            float e = aA + adn; e = e > 0.f ? e : 0.2f * e;
            float x = __expf(e); den += x; acc = fmaf(x, vA, acc);
        }
        if (i + 1 < e1) { float e = aB + adn; e = e > 0.f ? e : 0.2f * e;
                          float x = __expf(e); den += x; acc = fmaf(x, vB, acc); }
        if (i + 2 < e1) { float e = aC + adn; e = e > 0.f ? e : 0.2f * e;
                          float x = __expf(e); den += x; acc = fmaf(x, vC, acc); }
        if (i + 3 < e1) { float e = aD + adn; e = e > 0.f ? e : 0.2f * e;
                          float x = __expf(e); den += x; acc = fmaf(x, vD, acc); }
    }
    if (lane < 32) out[(size_t)node * 32 + lane] = acc / (den + 1e-16f) + b2[lane];
}

extern "C" void kernel_launch(void* const* d_in, const int* in_sizes, int n_in,
                              void* d_out, int out_size, void* d_ws, size_t ws_size,
                              hipStream_t stream) {
    const float* x    = (const float*)d_in[0];
    const int*   ei   = (const int*)d_in[1];
    const float* W1   = (const float*)d_in[2];
    const float* as1  = (const float*)d_in[3];
    const float* ad1  = (const float*)d_in[4];
    const float* b1   = (const float*)d_in[5];
    const float* W2   = (const float*)d_in[6];
    const float* as2  = (const float*)d_in[7];
    const float* ad2  = (const float*)d_in[8];
    const float* b2   = (const float*)d_in[9];
    int n = in_sizes[0] / 128;
    int E = in_sizes[1] / 2;

    char* w = (char*)d_ws;
    auto alloc = [&](size_t bytes) -> char* {
        char* p = w; w += (bytes + 255) / 256 * 256; return p;
    };
    int*   deg     = (int*)alloc((size_t)n * 4);
    int*   row_ptr = (int*)alloc((size_t)n * 4);
    int*   cursor  = (int*)alloc((size_t)n * 4);
    int*   bsum    = (int*)alloc(1024);
    int*   col     = (int*)alloc((size_t)E * 4);
    float* xl1     = (float*)alloc((size_t)n * 64 * 4);   // reused as xl2
    float* sc1     = (float*)alloc((size_t)n * 4 * 4);    // reused as sc2
    float* h       = (float*)alloc((size_t)n * 64 * 4);
    float* xl2 = xl1;
    float* sc2 = sc1;

    hipMemsetAsync(deg, 0, (size_t)n * 4, stream);
    int gN  = (n + BS - 1) / BS;
    int nb1 = (n + 1023) / 1024;
    int gW  = (n + 3) / 4;                    // 4 waves (nodes) per 256-thread block
    int S   = (E + BS * 4 - 1) / (BS * 4);    // slices per phase
    int gP  = 8 * S;                          // phase-partitioned grid

    k_hist   <<<gP, BS, 0, stream>>>(ei, E, n, deg);
    k_scan1  <<<nb1, BS, 0, stream>>>(deg, n, row_ptr, bsum);
    k_scan2  <<<1, BS, 0, stream>>>(bsum, nb1);
    k_scan3  <<<gN, BS, 0, stream>>>(row_ptr, cursor, bsum, n);
    k_scatter<<<gP, BS, 0, stream>>>(ei, E, n, cursor, col);
    k_gemm1  <<<gN, BS, 0, stream>>>(x, W1, as1, ad1, xl1, sc1, n);
    k_agg1   <<<gW, BS, 0, stream>>>(row_ptr, cursor, col, xl1, sc1, b1, h, n);
    k_gemm2  <<<gN, BS, 0, stream>>>(h, W2, as2, ad2, xl2, sc2, n);
    k_agg2   <<<gW, BS, 0, stream>>>(row_ptr, cursor, col, xl2, sc2, b2, (float*)d_out, n);
}